// Round 1
// baseline (11.330 us; speedup 1.0000x reference)
//
#include <hip/hip_runtime.h>

#define IMG_W 512
#define IMG_HW (512 * 512)
#define IMG_CHW (3 * 512 * 512)

// One wave64 per patch pair. 192 elements per patch -> 3 per lane.
__global__ __launch_bounds__(256) void patch_stats_kernel(
    const float* __restrict__ gen, const float* __restrict__ tgt,
    const int* __restrict__ y_gen, const int* __restrict__ x_gen,
    const int* __restrict__ y_tgt, const int* __restrict__ x_tgt,
    float* __restrict__ ws)
{
    const int wave  = threadIdx.x >> 6;
    const int lane  = threadIdx.x & 63;
    const int patch = blockIdx.x * 4 + wave;   // 0..2047  (== b*64 + n)
    const int b     = patch >> 6;

    const int yg = y_gen[patch], xg = x_gen[patch];
    const int yt = y_tgt[patch], xt = x_tgt[patch];

    const float* __restrict__ gbase = gen + (size_t)b * IMG_CHW;
    const float* __restrict__ tbase = tgt + (size_t)b * IMG_CHW;

    float gv[3], tv[3];
    #pragma unroll
    for (int k = 0; k < 3; ++k) {
        const int e   = lane + 64 * k;       // 0..191
        const int c   = e >> 6;              // channel
        const int r   = (e >> 3) & 7;        // patch row
        const int col = e & 7;               // patch col
        gv[k] = gbase[c * IMG_HW + (yg + r) * IMG_W + xg + col];
        tv[k] = tbase[c * IMG_HW + (yt + r) * IMG_W + xt + col];
    }

    // pass 1: sums -> means
    float gs = gv[0] + gv[1] + gv[2];
    float ts = tv[0] + tv[1] + tv[2];
    #pragma unroll
    for (int off = 32; off; off >>= 1) {
        gs += __shfl_xor(gs, off, 64);
        ts += __shfl_xor(ts, off, 64);
    }
    const float gmean = gs * (1.0f / 192.0f);
    const float tmean = ts * (1.0f / 192.0f);

    // pass 2: sum of squared deviations -> unbiased var (n-1 = 191)
    float gss = 0.0f, tss = 0.0f;
    #pragma unroll
    for (int k = 0; k < 3; ++k) {
        const float dg = gv[k] - gmean; gss += dg * dg;
        const float dt = tv[k] - tmean; tss += dt * dt;
    }
    #pragma unroll
    for (int off = 32; off; off >>= 1) {
        gss += __shfl_xor(gss, off, 64);
        tss += __shfl_xor(tss, off, 64);
    }

    if (lane == 0) {
        const float gvar = gss * (1.0f / 191.0f);
        const float tvar = tss * (1.0f / 191.0f);
        const float dm = gmean - tmean;
        const float dv = gvar - tvar;
        ws[patch] = dm * dm + dv * dv;
    }
}

// Deterministic final reduction of 2048 partials -> scalar mean-loss + var-loss.
__global__ __launch_bounds__(256) void final_reduce_kernel(
    const float* __restrict__ ws, float* __restrict__ out)
{
    float s = 0.0f;
    #pragma unroll
    for (int k = 0; k < 8; ++k) s += ws[threadIdx.x + 256 * k];
    #pragma unroll
    for (int off = 32; off; off >>= 1) s += __shfl_xor(s, off, 64);

    __shared__ float partial[4];
    if ((threadIdx.x & 63) == 0) partial[threadIdx.x >> 6] = s;
    __syncthreads();
    if (threadIdx.x == 0) {
        const float t = partial[0] + partial[1] + partial[2] + partial[3];
        out[0] = t * (1.0f / 2048.0f);
    }
}

extern "C" void kernel_launch(void* const* d_in, const int* in_sizes, int n_in,
                              void* d_out, int out_size, void* d_ws, size_t ws_size,
                              hipStream_t stream) {
    const float* gen = (const float*)d_in[0];
    const float* tgt = (const float*)d_in[1];
    const int*   yg  = (const int*)d_in[2];
    const int*   xg  = (const int*)d_in[3];
    const int*   yt  = (const int*)d_in[4];
    const int*   xt  = (const int*)d_in[5];
    float* out = (float*)d_out;
    float* ws  = (float*)d_ws;

    // 2048 patch pairs, 4 waves (patches) per 256-thread block -> 512 blocks
    patch_stats_kernel<<<512, 256, 0, stream>>>(gen, tgt, yg, xg, yt, xt, ws);
    final_reduce_kernel<<<1, 256, 0, stream>>>(ws, out);
}